// Round 4
// baseline (988.543 us; speedup 1.0000x reference)
//
#include <hip/hip_runtime.h>

typedef __bf16 bf16;
typedef __bf16 bf16x8 __attribute__((ext_vector_type(8)));
typedef __bf16 bf16x4 __attribute__((ext_vector_type(4)));
typedef float floatx4 __attribute__((ext_vector_type(4)));

typedef __attribute__((address_space(1))) const void gvoid_t;
typedef __attribute__((address_space(3))) void lvoid_t;

#define B_DIM 8
#define S_DIM 4096
#define M_DIM 32768
#define CHUNK 128
#define NCHUNK 32

__device__ __forceinline__ void gload_lds16(const bf16* g, bf16* l) {
    __builtin_amdgcn_global_load_lds((gvoid_t*)g, (lvoid_t*)l, 16, 0, 0);
}

__device__ __forceinline__ float gelu_tanh(float x) {
    float x3 = x * x * x;
    return 0.5f * x * (1.0f + tanhf(0.7978845608028654f * (x + 0.044715f * x3)));
}

__device__ __forceinline__ float sigmoidf(float z) {
    return 1.0f / (1.0f + expf(-z));
}

// ---------------- weight transpose (f32 -> bf16, W^T), LDS-tiled ----------------
// mz 0..3 -> T[n*1024+k]; mz 4 -> Bcat[n*2048+k]; mz 5 -> Bcat[n*2048+1024+k]
__global__ void prep_weights(const float* __restrict__ W0, const float* __restrict__ W1,
                             const float* __restrict__ W2, const float* __restrict__ W3,
                             const float* __restrict__ W4, const float* __restrict__ W5,
                             bf16* __restrict__ T0, bf16* __restrict__ T1,
                             bf16* __restrict__ T2, bf16* __restrict__ T3,
                             bf16* __restrict__ Bcat) {
    __shared__ float tile[32][33];
    int mz = blockIdx.z;
    const float* W = mz == 0 ? W0 : mz == 1 ? W1 : mz == 2 ? W2 : mz == 3 ? W3 : mz == 4 ? W4 : W5;
    int tn = blockIdx.x * 32;
    int tk = blockIdx.y * 32;
    int tx = threadIdx.x & 31, ty = threadIdx.x >> 5;   // ty 0..7
#pragma unroll
    for (int i = 0; i < 4; ++i)
        tile[ty + i * 8][tx] = W[(size_t)(tk + ty + i * 8) * 1024 + tn + tx];
    __syncthreads();
    if (mz < 4) {
        bf16* T = mz == 0 ? T0 : mz == 1 ? T1 : mz == 2 ? T2 : T3;
#pragma unroll
        for (int i = 0; i < 4; ++i)
            T[(size_t)(tn + ty + i * 8) * 1024 + tk + tx] = (bf16)tile[tx][ty + i * 8];
    } else {
        int koff = (mz == 5) ? 1024 : 0;
#pragma unroll
        for (int i = 0; i < 4; ++i)
            Bcat[(size_t)(tn + ty + i * 8) * 2048 + koff + tk + tx] = (bf16)tile[tx][ty + i * 8];
    }
}

__global__ void sp_kernel(const float* __restrict__ a_param, float* __restrict__ spbuf) {
    int d = blockIdx.x * 256 + threadIdx.x;
    spbuf[d] = log1pf(expf(a_param[d]));
}

// ---------------- gelu: x (f32) -> xg (bf16) ----------------
__global__ void gelu_kernel(const float* __restrict__ x, bf16* __restrict__ xg) {
    size_t i = (size_t)blockIdx.x * 256 + threadIdx.x;   // over n/4 elements
    float4 v = ((const float4*)x)[i];
    bf16x4 o;
    o[0] = (bf16)gelu_tanh(v.x); o[1] = (bf16)gelu_tanh(v.y);
    o[2] = (bf16)gelu_tanh(v.z); o[3] = (bf16)gelu_tanh(v.w);
    ((bf16x4*)xg)[i] = o;
}

// ---------------- dual-B GEMM: two C tiles (same m,n) from one A ----------------
// MODE 0 (UV):    out1 = bf16(acc1 + bias1)  [u]; out2 = bf16(acc2 + bias2)  [v]
// MODE 1 (GATES): la = -8*sigmoid(acc2+bias2)*sp[gn] -> out2 (bf16)
//                 sc = sqrt(-expm1(2la))*sigmoid(acc1+bias1)*vbuf[o] -> out1 (bf16)
template <int MODE>
__launch_bounds__(256, 2)
__global__ void gemm_dual(const bf16* __restrict__ A, const bf16* __restrict__ B1t,
                          const bf16* __restrict__ B2t,
                          bf16* __restrict__ out1, bf16* __restrict__ out2,
                          const float* __restrict__ bias1, const float* __restrict__ bias2,
                          const float* __restrict__ spbuf, const bf16* __restrict__ vbuf) {
    __shared__ __align__(16) bf16 lsA[128 * 64];
    __shared__ __align__(16) bf16 lsB1[128 * 64];
    __shared__ __align__(16) bf16 lsB2[128 * 64];
    const int tid = threadIdx.x;
    const int wave = tid >> 6;
    const int lane = tid & 63;
    const int lane15 = lane & 15;
    const int quad = lane >> 4;
    const int wm = wave & 1, wn = wave >> 1;
    // XCD-aware swizzle: 2048 blocks = 8 XCDs x 32 m-tiles x 8 n-tiles
    const int blk = blockIdx.x;
    const int xcd = blk & 7;
    const int j = blk >> 3;
    const long m0 = (long)(xcd * 32 + (j >> 3)) * 128;
    const long n0 = (long)(j & 7) * 128;
    const int r_in = lane >> 3;
    const int cch = lane & 7;

    floatx4 acc1[4][4] = {};
    floatx4 acc2[4][4] = {};

    for (int kt = 0; kt < 16; ++kt) {
        __syncthreads();
#pragma unroll
        for (int i = 0; i < 4; ++i) {
            int rr = (i * 4 + wave) * 8 + r_in;
            int g = cch ^ (rr & 7);
            gload_lds16(A + (size_t)(m0 + rr) * 1024 + kt * 64 + g * 8, &lsA[(i * 4 + wave) * 512]);
            gload_lds16(B1t + (size_t)(n0 + rr) * 1024 + kt * 64 + g * 8, &lsB1[(i * 4 + wave) * 512]);
            gload_lds16(B2t + (size_t)(n0 + rr) * 1024 + kt * 64 + g * 8, &lsB2[(i * 4 + wave) * 512]);
        }
        __syncthreads();
#pragma unroll
        for (int kk = 0; kk < 2; ++kk) {
            bf16x8 af[4], b1f[4], b2f[4];
#pragma unroll
            for (int mi = 0; mi < 4; ++mi) {
                int ml = wm * 64 + mi * 16 + lane15;
                af[mi] = *(const bf16x8*)&lsA[ml * 64 + ((kk * 4 + quad) ^ (ml & 7)) * 8];
            }
#pragma unroll
            for (int ni = 0; ni < 4; ++ni) {
                int nl = wn * 64 + ni * 16 + lane15;
                int idx = nl * 64 + ((kk * 4 + quad) ^ (nl & 7)) * 8;
                b1f[ni] = *(const bf16x8*)&lsB1[idx];
                b2f[ni] = *(const bf16x8*)&lsB2[idx];
            }
#pragma unroll
            for (int mi = 0; mi < 4; ++mi)
#pragma unroll
                for (int ni = 0; ni < 4; ++ni) {
                    acc1[mi][ni] = __builtin_amdgcn_mfma_f32_16x16x32_bf16(af[mi], b1f[ni], acc1[mi][ni], 0, 0, 0);
                    acc2[mi][ni] = __builtin_amdgcn_mfma_f32_16x16x32_bf16(af[mi], b2f[ni], acc2[mi][ni], 0, 0, 0);
                }
        }
    }

#pragma unroll
    for (int mi = 0; mi < 4; ++mi) {
#pragma unroll
        for (int ni = 0; ni < 4; ++ni) {
            floatx4 v1 = acc1[mi][ni];
            floatx4 v2 = acc2[mi][ni];
            long gn = n0 + wn * 64 + ni * 16 + lane15;
            float bb1 = bias1[gn], bb2 = bias2[gn];
            float sp = (MODE == 1) ? spbuf[gn] : 0.0f;
#pragma unroll
            for (int r = 0; r < 4; ++r) {
                long gm = m0 + wm * 64 + mi * 16 + quad * 4 + r;
                size_t o = (size_t)gm * 1024 + gn;
                if (MODE == 0) {
                    out1[o] = (bf16)(v1[r] + bb1);
                    out2[o] = (bf16)(v2[r] + bb2);
                } else {
                    float za = v2[r] + bb2;
                    float la = -8.0f * sigmoidf(za) * sp;
                    out2[o] = (bf16)la;
                    float zx = v1[r] + bb1;
                    float sc = sqrtf(-expm1f(2.0f * la)) * sigmoidf(zx) * (float)vbuf[o];
                    out1[o] = (bf16)sc;
                }
            }
        }
    }
}

// ---------------- final GEMM: out[M][1024] = [A1|A2] @ Bcat^T, K=2048 ----------------
__launch_bounds__(256, 2)
__global__ void gemm_fin(const bf16* __restrict__ A1, const bf16* __restrict__ A2,
                         const bf16* __restrict__ Bcat, float* __restrict__ out,
                         const float* __restrict__ bias1, const float* __restrict__ bias2,
                         const float* __restrict__ xres) {
    __shared__ __align__(16) bf16 lsA[128 * 64];
    __shared__ __align__(16) bf16 lsB[128 * 64];
    const int tid = threadIdx.x;
    const int wave = tid >> 6;
    const int lane = tid & 63;
    const int lane15 = lane & 15;
    const int quad = lane >> 4;
    const int wm = wave & 1, wn = wave >> 1;
    const int blk = blockIdx.x;
    const int xcd = blk & 7;
    const int j = blk >> 3;
    const long m0 = (long)(xcd * 32 + (j >> 3)) * 128;
    const long n0 = (long)(j & 7) * 128;
    const int r_in = lane >> 3;
    const int cch = lane & 7;

    floatx4 acc[4][4] = {};

    for (int kt = 0; kt < 32; ++kt) {
        const bf16* Asrc = (kt < 16) ? A1 : A2;
        int ktt = kt & 15;
        __syncthreads();
#pragma unroll
        for (int i = 0; i < 4; ++i) {
            int rr = (i * 4 + wave) * 8 + r_in;
            int g = cch ^ (rr & 7);
            gload_lds16(Asrc + (size_t)(m0 + rr) * 1024 + ktt * 64 + g * 8, &lsA[(i * 4 + wave) * 512]);
            gload_lds16(Bcat + (size_t)(n0 + rr) * 2048 + kt * 64 + g * 8, &lsB[(i * 4 + wave) * 512]);
        }
        __syncthreads();
#pragma unroll
        for (int kk = 0; kk < 2; ++kk) {
            bf16x8 af[4], bfr[4];
#pragma unroll
            for (int mi = 0; mi < 4; ++mi) {
                int ml = wm * 64 + mi * 16 + lane15;
                af[mi] = *(const bf16x8*)&lsA[ml * 64 + ((kk * 4 + quad) ^ (ml & 7)) * 8];
            }
#pragma unroll
            for (int ni = 0; ni < 4; ++ni) {
                int nl = wn * 64 + ni * 16 + lane15;
                bfr[ni] = *(const bf16x8*)&lsB[nl * 64 + ((kk * 4 + quad) ^ (nl & 7)) * 8];
            }
#pragma unroll
            for (int mi = 0; mi < 4; ++mi)
#pragma unroll
                for (int ni = 0; ni < 4; ++ni)
                    acc[mi][ni] = __builtin_amdgcn_mfma_f32_16x16x32_bf16(af[mi], bfr[ni], acc[mi][ni], 0, 0, 0);
        }
    }

#pragma unroll
    for (int mi = 0; mi < 4; ++mi) {
#pragma unroll
        for (int ni = 0; ni < 4; ++ni) {
            floatx4 v = acc[mi][ni];
            long gn = n0 + wn * 64 + ni * 16 + lane15;
            float bb = bias1[gn] + bias2[gn];
#pragma unroll
            for (int r = 0; r < 4; ++r) {
                long gm = m0 + wm * 64 + mi * 16 + quad * 4 + r;
                size_t o = (size_t)gm * 1024 + gn;
                out[o] = v[r] + bb + xres[o];
            }
        }
    }
}

// ---------------- forward scan (3-pass chunked, bf16 u, 4 d's per thread) ----------------
__global__ void fscan1(const bf16* __restrict__ u, const float* __restrict__ a_fwd,
                       float* __restrict__ carry) {
    int b = blockIdx.x >> 5, c = blockIdx.x & 31;
    int d0 = threadIdx.x * 4;
    float4 a4 = *(const float4*)(a_fwd + d0);
    const bf16* up = u + ((size_t)(b * S_DIM + c * CHUNK)) * 1024 + d0;
    float h0 = 0, h1 = 0, h2 = 0, h3 = 0;
#pragma unroll 4
    for (int t = 0; t < CHUNK; ++t) {
        bf16x4 uv = *(const bf16x4*)(up + (size_t)t * 1024);
        h0 = fmaf(a4.x, h0, (float)uv[0]);
        h1 = fmaf(a4.y, h1, (float)uv[1]);
        h2 = fmaf(a4.z, h2, (float)uv[2]);
        h3 = fmaf(a4.w, h3, (float)uv[3]);
    }
    float4 st = {h0, h1, h2, h3};
    *(float4*)(carry + ((size_t)c * 8 + b) * 1024 + d0) = st;
}
__global__ void fscan2(const float* __restrict__ carry, const float* __restrict__ a_fwd,
                       float* __restrict__ H) {
    int idx = blockIdx.x * 256 + threadIdx.x;   // 8192 chains
    int d = idx & 1023, b = idx >> 10;
    float a = a_fwd[d];
    float aL = a;
#pragma unroll
    for (int i = 0; i < 7; ++i) aL *= aL;       // a^128
    float h = 0.0f;
    for (int c = 0; c < NCHUNK; ++c) {
        size_t o = ((size_t)c * 8 + b) * 1024 + d;
        H[o] = h;
        h = fmaf(aL, h, carry[o]);
    }
}
__global__ void fscan3(const bf16* __restrict__ u, const float* __restrict__ a_fwd,
                       const float* __restrict__ H, bf16* __restrict__ hf) {
    int b = blockIdx.x >> 5, c = blockIdx.x & 31;
    int d0 = threadIdx.x * 4;
    float4 a4 = *(const float4*)(a_fwd + d0);
    const bf16* up = u + ((size_t)(b * S_DIM + c * CHUNK)) * 1024 + d0;
    bf16* op = hf + ((size_t)(b * S_DIM + c * CHUNK)) * 1024 + d0;
    float4 h = *(const float4*)(H + ((size_t)c * 8 + b) * 1024 + d0);
#pragma unroll 4
    for (int t = 0; t < CHUNK; ++t) {
        bf16x4 uv = *(const bf16x4*)(up + (size_t)t * 1024);
        h.x = fmaf(a4.x, h.x, (float)uv[0]);
        h.y = fmaf(a4.y, h.y, (float)uv[1]);
        h.z = fmaf(a4.z, h.z, (float)uv[2]);
        h.w = fmaf(a4.w, h.w, (float)uv[3]);
        bf16x4 o = {(bf16)h.x, (bf16)h.y, (bf16)h.z, (bf16)h.w};
        *(bf16x4*)(op + (size_t)t * 1024) = o;
    }
}

// ---------------- reverse RG-LRU scan (3-pass chunked, 4 d's per thread) ----------------
__global__ void bscan1(const bf16* __restrict__ la, const bf16* __restrict__ sc,
                       float* __restrict__ BL, float* __restrict__ BP) {
    int b = blockIdx.x >> 5, c = blockIdx.x & 31;
    int d0 = threadIdx.x * 4;
    const bf16* lap = la + ((size_t)(b * S_DIM + c * CHUNK)) * 1024 + d0;
    const bf16* gp = sc + ((size_t)(b * S_DIM + c * CHUNK)) * 1024 + d0;
    float h0 = 0, h1 = 0, h2 = 0, h3 = 0;
    float s0 = 0, s1 = 0, s2 = 0, s3 = 0;
#pragma unroll 4
    for (int t = CHUNK - 1; t >= 0; --t) {
        bf16x4 lv = *(const bf16x4*)(lap + (size_t)t * 1024);
        bf16x4 gv = *(const bf16x4*)(gp + (size_t)t * 1024);
        float l0 = (float)lv[0], l1 = (float)lv[1], l2 = (float)lv[2], l3 = (float)lv[3];
        h0 = fmaf(expf(l0), h0, (float)gv[0]); s0 += l0;
        h1 = fmaf(expf(l1), h1, (float)gv[1]); s1 += l1;
        h2 = fmaf(expf(l2), h2, (float)gv[2]); s2 += l2;
        h3 = fmaf(expf(l3), h3, (float)gv[3]); s3 += l3;
    }
    size_t o = ((size_t)c * 8 + b) * 1024 + d0;
    float4 hl = {h0, h1, h2, h3};
    float4 pp = {expf(s0), expf(s1), expf(s2), expf(s3)};
    *(float4*)(BL + o) = hl;
    *(float4*)(BP + o) = pp;
}
__global__ void bscan2(const float* __restrict__ BL, const float* __restrict__ BP,
                       float* __restrict__ R) {
    int idx = blockIdx.x * 256 + threadIdx.x;   // 8192 chains
    int d = idx & 1023, b = idx >> 10;
    float r = 0.0f;
    for (int c = NCHUNK - 1; c >= 0; --c) {
        size_t o = ((size_t)c * 8 + b) * 1024 + d;
        R[o] = r;
        r = fmaf(BP[o], r, BL[o]);
    }
}
__global__ void bscan3(const bf16* __restrict__ la, const bf16* __restrict__ sc,
                       const float* __restrict__ R, bf16* __restrict__ hb) {
    int b = blockIdx.x >> 5, c = blockIdx.x & 31;
    int d0 = threadIdx.x * 4;
    const bf16* lap = la + ((size_t)(b * S_DIM + c * CHUNK)) * 1024 + d0;
    const bf16* gp = sc + ((size_t)(b * S_DIM + c * CHUNK)) * 1024 + d0;
    bf16* op = hb + ((size_t)(b * S_DIM + c * CHUNK)) * 1024 + d0;
    float4 h = *(const float4*)(R + ((size_t)c * 8 + b) * 1024 + d0);
#pragma unroll 4
    for (int t = CHUNK - 1; t >= 0; --t) {
        bf16x4 lv = *(const bf16x4*)(lap + (size_t)t * 1024);
        bf16x4 gv = *(const bf16x4*)(gp + (size_t)t * 1024);
        h.x = fmaf(expf((float)lv[0]), h.x, (float)gv[0]);
        h.y = fmaf(expf((float)lv[1]), h.y, (float)gv[1]);
        h.z = fmaf(expf((float)lv[2]), h.z, (float)gv[2]);
        h.w = fmaf(expf((float)lv[3]), h.w, (float)gv[3]);
        bf16x4 o = {(bf16)h.x, (bf16)h.y, (bf16)h.z, (bf16)h.w};
        *(bf16x4*)(op + (size_t)t * 1024) = o;
    }
}

extern "C" void kernel_launch(void* const* d_in, const int* in_sizes, int n_in,
                              void* d_out, int out_size, void* d_ws, size_t ws_size,
                              hipStream_t stream) {
    const float* x       = (const float*)d_in[0];
    const float* a_fwd   = (const float*)d_in[1];
    const float* Wf1     = (const float*)d_in[2];
    const float* bf1     = (const float*)d_in[3];
    const float* Wf2     = (const float*)d_in[4];
    const float* bf2     = (const float*)d_in[5];
    const float* Wbx     = (const float*)d_in[6];
    const float* bbx     = (const float*)d_in[7];
    const float* Wgx     = (const float*)d_in[8];
    const float* bgx     = (const float*)d_in[9];
    const float* Wga     = (const float*)d_in[10];
    const float* bga     = (const float*)d_in[11];
    const float* a_param = (const float*)d_in[12];
    const float* Wb2     = (const float*)d_in[13];
    const float* bb2     = (const float*)d_in[14];
    float* out = (float*)d_out;
    (void)in_sizes; (void)n_in; (void)out_size; (void)ws_size;

    // ---- workspace layout (~205 MB) ----
    char* ws = (char*)d_ws;
    size_t off = 0;
    const size_t WSZ = (size_t)1024 * 1024 * 2;          // 2 MB per transposed weight
    bf16* Wf1t = (bf16*)(ws + off); off += WSZ;
    bf16* Wbxt = (bf16*)(ws + off); off += WSZ;
    bf16* Wgxt = (bf16*)(ws + off); off += WSZ;
    bf16* Wgat = (bf16*)(ws + off); off += WSZ;
    bf16* Bcat = (bf16*)(ws + off); off += 2 * WSZ;      // [1024][2048] = [Wf2t|Wb2t] k-concat
    float* spbuf = (float*)(ws + off); off += 4096;
    const size_t BSZ = (size_t)M_DIM * 1024 * 2;         // 64 MB bf16 [M][1024]
    bf16* buf0 = (bf16*)(ws + off); off += BSZ;          // xg -> hf
    bf16* buf1 = (bf16*)(ws + off); off += BSZ;          // v  -> hb
    bf16* buf2 = (bf16*)(ws + off); off += BSZ;          // la
    float* Fc = (float*)(ws + off); off += (size_t)NCHUNK * 8 * 1024 * 4;
    float* FH = (float*)(ws + off); off += (size_t)NCHUNK * 8 * 1024 * 4;
    float* BL = (float*)(ws + off); off += (size_t)NCHUNK * 8 * 1024 * 4;
    float* BP = (float*)(ws + off); off += (size_t)NCHUNK * 8 * 1024 * 4;
    float* BR = (float*)(ws + off); off += (size_t)NCHUNK * 8 * 1024 * 4;

    bf16* xg = buf0;
    bf16* hf = buf0;                          // xg dead before hf written
    bf16* vb = buf1;
    bf16* hb = buf1;                          // v dead before hb written
    bf16* la = buf2;
    bf16* u  = (bf16*)d_out;                  // first 64 MB of d_out (dead before final GEMM)
    bf16* sc = (bf16*)d_out + (size_t)M_DIM * 1024;   // second 64 MB (dead before final GEMM)

    // 1. prep: transposed bf16 weights (+k-concat final B) + softplus(a_param)
    prep_weights<<<dim3(32, 32, 6), 256, 0, stream>>>(Wf1, Wbx, Wgx, Wga, Wf2, Wb2,
                                                      Wf1t, Wbxt, Wgxt, Wgat, Bcat);
    sp_kernel<<<4, 256, 0, stream>>>(a_param, spbuf);
    // 2. gelu
    gelu_kernel<<<32768, 256, 0, stream>>>(x, xg);
    // 3. dual GEMM A: u = xg@Wf1+bf1 (bf16, d_out lo), v = xg@Wbx+bbx (bf16)
    gemm_dual<0><<<2048, 256, 0, stream>>>(xg, Wf1t, Wbxt, u, vb, bf1, bbx, nullptr, nullptr);
    // 4. forward scan -> hf (bf16, overwrites xg)
    fscan1<<<256, 256, 0, stream>>>(u, a_fwd, Fc);
    fscan2<<<32, 256, 0, stream>>>(Fc, a_fwd, FH);
    fscan3<<<256, 256, 0, stream>>>(u, a_fwd, FH, hf);
    // 5. dual GEMM gates: la (bf16), sc (bf16, d_out hi) in ONE pass over v
    gemm_dual<1><<<2048, 256, 0, stream>>>(vb, Wgxt, Wgat, sc, la, bgx, bga, spbuf, vb);
    // 6. reverse scan -> hb (bf16, overwrites v)
    bscan1<<<256, 256, 0, stream>>>(la, sc, BL, BP);
    bscan2<<<32, 256, 0, stream>>>(BL, BP, BR);
    bscan3<<<256, 256, 0, stream>>>(la, sc, BR, hb);
    // 7. final GEMM K=2048: out = [hf|hb]@[Wf2;Wb2] + bf2 + bb2 + x
    gemm_fin<<<2048, 256, 0, stream>>>(hf, hb, Bcat, out, bf2, bb2, x);
}